// Round 1
// baseline (106.109 us; speedup 1.0000x reference)
//
#include <hip/hip_runtime.h>

// 3x3 zero-padded median filter over (B=16, C=3, H=512, W=512) fp32.
// Memory-bound: ~50 MB in + 50 MB out. One thread = 4 output columns
// (float4 load/store), 128 threads/row, 2 rows per 256-thread block.

#define S2(a, b) { float _t = fminf(a, b); b = fmaxf(a, b); a = _t; }
#define MN3(a, b, c) S2(a, b); S2(a, c);
#define MX3(a, b, c) S2(b, c); S2(a, c);
#define MNMX3(a, b, c) MX3(a, b, c); S2(a, b);
#define MNMX4(a, b, c, d) S2(a, b); S2(c, d); S2(a, c); S2(b, d);
#define MNMX5(a, b, c, d, e) S2(a, b); S2(c, d); MN3(a, c, e); MX3(b, d, e);
#define MNMX6(a, b, c, d, e, f) S2(a, d); S2(b, e); S2(c, f); MN3(a, b, c); MX3(d, e, f);

__device__ __forceinline__ float med9(float p0, float p1, float p2,
                                      float p3, float p4, float p5,
                                      float p6, float p7, float p8) {
    // McGuire's median-of-9 network (20 exchanges); median lands in p4.
    MNMX6(p0, p1, p2, p3, p4, p5);
    MNMX5(p1, p2, p3, p4, p6);
    MNMX4(p2, p3, p4, p7);
    MNMX3(p3, p4, p8);
    return p4;
}

// H = W = 512 hardcoded (shift/mask tricks); IMGS = B*C = 48.
__global__ __launch_bounds__(256)
void median3x3_kernel(const float* __restrict__ in, float* __restrict__ out) {
    const int tid      = threadIdx.x;
    const int lane     = tid & 127;        // 128 threads per row (4 cols each)
    const int rowInBlk = tid >> 7;         // 2 rows per block
    const int grow     = blockIdx.x * 2 + rowInBlk;  // global row across all images
    const int img      = grow >> 9;        // / 512
    const int y        = grow & 511;       // % 512
    const int x        = lane << 2;        // 4 cols per thread

    const size_t imgBase = (size_t)img * (512 * 512);
    const float* __restrict__ base = in + imgBase;

    // r[d][0..5] = input columns [x-1 .. x+4] of row y+d-1 (zero padded).
    float r[3][6];
#pragma unroll
    for (int d = 0; d < 3; ++d) {
        const int ry = y + d - 1;
        if (ry >= 0 && ry < 512) {
            const float* rp = base + ((size_t)ry << 9) + x;
            const float4 f = *(const float4*)rp;
            r[d][1] = f.x; r[d][2] = f.y; r[d][3] = f.z; r[d][4] = f.w;
            r[d][0] = (x > 0)       ? rp[-1] : 0.0f;
            r[d][5] = (x + 4 < 512) ? rp[4]  : 0.0f;
        } else {
#pragma unroll
            for (int j = 0; j < 6; ++j) r[d][j] = 0.0f;
        }
    }

    float4 o;
    float* op = &o.x;
#pragma unroll
    for (int j = 0; j < 4; ++j) {
        op[j] = med9(r[0][j], r[0][j + 1], r[0][j + 2],
                     r[1][j], r[1][j + 1], r[1][j + 2],
                     r[2][j], r[2][j + 1], r[2][j + 2]);
    }

    *(float4*)(out + imgBase + ((size_t)y << 9) + x) = o;
}

extern "C" void kernel_launch(void* const* d_in, const int* in_sizes, int n_in,
                              void* d_out, int out_size, void* d_ws, size_t ws_size,
                              hipStream_t stream) {
    const float* x = (const float*)d_in[0];
    float* out = (float*)d_out;
    // 48 images * 512 rows / 2 rows-per-block = 12288 blocks of 256 threads.
    const int grid = 48 * 512 / 2;
    median3x3_kernel<<<grid, 256, 0, stream>>>(x, out);
}

// Round 2
// 104.900 us; speedup vs baseline: 1.0115x; 1.0115x over previous
//
#include <hip/hip_runtime.h>

// 3x3 zero-padded median, (16,3,512,512) fp32, H=W=512, B*C=48 images.
// One wave = one 512-col row segment set: 64 lanes x 8 cols.
// Each wave walks an 8-row strip, rolling 3 rows in registers (4-slot
// buffer, 1-row prefetch). Column halos via shuffles -> no scalar loads.
// Block = 256 thr = 4 waves = 4 strips. 768 blocks; XCD-contiguous remap
// gives each XCD 6 whole images (no cross-XCD row sharing).

#define S2(a, b) { float _t = fminf(a, b); b = fmaxf(a, b); a = _t; }
#define MN3(a, b, c) S2(a, b); S2(a, c);
#define MX3(a, b, c) S2(b, c); S2(a, c);
#define MNMX3(a, b, c) MX3(a, b, c); S2(a, b);
#define MNMX4(a, b, c, d) S2(a, b); S2(c, d); S2(a, c); S2(b, d);
#define MNMX5(a, b, c, d, e) S2(a, b); S2(c, d); MN3(a, c, e); MX3(b, d, e);
#define MNMX6(a, b, c, d, e, f) S2(a, d); S2(b, e); S2(c, f); MN3(a, b, c); MX3(d, e, f);

__device__ __forceinline__ float med9(float p0, float p1, float p2,
                                      float p3, float p4, float p5,
                                      float p6, float p7, float p8) {
    // McGuire's median-of-9 network (20 exchanges); median lands in p4.
    MNMX6(p0, p1, p2, p3, p4, p5);
    MNMX5(p1, p2, p3, p4, p6);
    MNMX4(p2, p3, p4, p7);
    MNMX3(p3, p4, p8);
    return p4;
}

// Load one image row (img_y may be -1 or 512 -> zero row) into v[0..9]:
// v[1..8] = cols [8L, 8L+8), v[0] = col 8L-1, v[9] = col 8L+8 (via shuffles).
__device__ __forceinline__ void load_row(const float* __restrict__ base,
                                         int img_y, int lane, float v[10]) {
    float4 f0, f1;
    if (img_y >= 0 && img_y < 512) {            // wave-uniform branch
        const float* rp = base + (img_y << 9) + (lane << 3);
        f0 = *(const float4*)rp;
        f1 = *(const float4*)(rp + 4);
    } else {
        f0 = make_float4(0.f, 0.f, 0.f, 0.f);
        f1 = f0;
    }
    float left  = __shfl_up(f1.w, 1);           // lane L-1's col 8L+7 == col 8L-1
    float right = __shfl_down(f0.x, 1);         // lane L+1's col 8L+8
    if (lane == 0)  left  = 0.f;                // image left edge (zero pad)
    if (lane == 63) right = 0.f;                // image right edge
    v[0] = left;
    v[1] = f0.x; v[2] = f0.y; v[3] = f0.z; v[4] = f0.w;
    v[5] = f1.x; v[6] = f1.y; v[7] = f1.z; v[8] = f1.w;
    v[9] = right;
}

__global__ __launch_bounds__(256)
void median3x3_kernel(const float* __restrict__ in, float* __restrict__ out) {
    const int lane = threadIdx.x & 63;
    const int wid  = threadIdx.x >> 6;

    // 768 blocks; XCD = blockIdx % 8. Remap so each XCD owns 96 consecutive
    // logical blocks -> 384 consecutive strips -> 6 whole images.
    const int lb    = (blockIdx.x & 7) * 96 + (blockIdx.x >> 3);
    const int strip = lb * 4 + wid;             // [0, 3072): 64 strips/image
    const int img   = strip >> 6;
    const int y0    = (strip & 63) << 3;        // first output row of strip

    const size_t imgBase = (size_t)img * (512 * 512);
    const float* __restrict__ base  = in  + imgBase;
    float*       __restrict__ obase = out + imgBase;

    // Rolling buffer: absolute input row i (= y0-1+i) lives in rows[i & 3].
    float rows[4][10];
    load_row(base, y0 - 1, lane, rows[0]);
    load_row(base, y0 + 0, lane, rows[1]);
    load_row(base, y0 + 1, lane, rows[2]);

#pragma unroll
    for (int t = 0; t < 8; ++t) {
        // Prefetch row for iteration t+1 before computing iteration t.
        if (t < 7) load_row(base, y0 + t + 2, lane, rows[(t + 3) & 3]);

        const float* ra = rows[t & 3];          // row y-1
        const float* rb = rows[(t + 1) & 3];    // row y
        const float* rc = rows[(t + 2) & 3];    // row y+1

        float m[8];
#pragma unroll
        for (int j = 0; j < 8; ++j)
            m[j] = med9(ra[j], ra[j + 1], ra[j + 2],
                        rb[j], rb[j + 1], rb[j + 2],
                        rc[j], rc[j + 1], rc[j + 2]);

        float* op = obase + ((size_t)(y0 + t) << 9) + (lane << 3);
        *(float4*)op       = make_float4(m[0], m[1], m[2], m[3]);
        *(float4*)(op + 4) = make_float4(m[4], m[5], m[6], m[7]);
    }
}

extern "C" void kernel_launch(void* const* d_in, const int* in_sizes, int n_in,
                              void* d_out, int out_size, void* d_ws, size_t ws_size,
                              hipStream_t stream) {
    const float* x = (const float*)d_in[0];
    float* out = (float*)d_out;
    // 48 images * 64 strips/image / 4 strips-per-block = 768 blocks.
    median3x3_kernel<<<768, 256, 0, stream>>>(x, out);
}

// Round 3
// 104.027 us; speedup vs baseline: 1.0200x; 1.0084x over previous
//
#include <hip/hip_runtime.h>

// 3x3 zero-padded median, (16,3,512,512) fp32, H=W=512, B*C=48 images.
// One wave (64 lanes x 8 cols = 512 cols) owns a 4-row strip: loads all 6
// input rows up-front (12 independent global_load_dwordx4 -> max MLP),
// column halos via shuffles, then 4x8 median-of-9 + 8 float4 stores.
// 6144 blocks x 64 thr = 24 waves/CU. XCD-contiguous remap: 6 images/XCD.

#define S2(a, b) { float _t = fminf(a, b); b = fmaxf(a, b); a = _t; }
#define MN3(a, b, c) S2(a, b); S2(a, c);
#define MX3(a, b, c) S2(b, c); S2(a, c);
#define MNMX3(a, b, c) MX3(a, b, c); S2(a, b);
#define MNMX4(a, b, c, d) S2(a, b); S2(c, d); S2(a, c); S2(b, d);
#define MNMX5(a, b, c, d, e) S2(a, b); S2(c, d); MN3(a, c, e); MX3(b, d, e);
#define MNMX6(a, b, c, d, e, f) S2(a, d); S2(b, e); S2(c, f); MN3(a, b, c); MX3(d, e, f);

__device__ __forceinline__ float med9(float p0, float p1, float p2,
                                      float p3, float p4, float p5,
                                      float p6, float p7, float p8) {
    // McGuire's median-of-9 network (20 exchanges); median lands in p4.
    MNMX6(p0, p1, p2, p3, p4, p5);
    MNMX5(p1, p2, p3, p4, p6);
    MNMX4(p2, p3, p4, p7);
    MNMX3(p3, p4, p8);
    return p4;
}

__global__ __launch_bounds__(64)
void median3x3_kernel(const float* __restrict__ in, float* __restrict__ out) {
    const int lane = threadIdx.x;               // 64 lanes, 8 cols each

    // 6144 blocks; XCD = blockIdx % 8. Remap so each XCD owns 768
    // consecutive strips = 6 whole images (no cross-XCD row sharing).
    const int strip = (blockIdx.x & 7) * 768 + (blockIdx.x >> 3);
    const int img   = strip >> 7;               // 128 strips per image
    const int y0    = (strip & 127) << 2;       // first output row

    const size_t imgBase = (size_t)img * (512 * 512);
    const float* __restrict__ base  = in  + imgBase;
    float*       __restrict__ obase = out + imgBase;
    const int xoff = lane << 3;

    // Phase 1: issue all 12 vector loads with no dependencies between them.
    float4 f0[6], f1[6];
#pragma unroll
    for (int d = 0; d < 6; ++d) {
        const int ry = y0 - 1 + d;
        if (ry >= 0 && ry < 512) {              // wave-uniform branch
            const float* rp = base + (ry << 9) + xoff;
            f0[d] = *(const float4*)rp;
            f1[d] = *(const float4*)(rp + 4);
        } else {
            f0[d] = make_float4(0.f, 0.f, 0.f, 0.f);
            f1[d] = f0[d];
        }
    }

    // Phase 2: halos via shuffles; assemble rows[d][0..9] = cols 8L-1..8L+8.
    float rows[6][10];
#pragma unroll
    for (int d = 0; d < 6; ++d) {
        float left  = __shfl_up(f1[d].w, 1);    // lane L-1's col 8L+7
        float right = __shfl_down(f0[d].x, 1);  // lane L+1's col 8L+8
        if (lane == 0)  left  = 0.f;            // image left edge (zero pad)
        if (lane == 63) right = 0.f;            // image right edge
        rows[d][0] = left;
        rows[d][1] = f0[d].x; rows[d][2] = f0[d].y;
        rows[d][3] = f0[d].z; rows[d][4] = f0[d].w;
        rows[d][5] = f1[d].x; rows[d][6] = f1[d].y;
        rows[d][7] = f1[d].z; rows[d][8] = f1[d].w;
        rows[d][9] = right;
    }

    // Phase 3: 4 output rows x 8 cols of median-of-9, float4 stores.
#pragma unroll
    for (int t = 0; t < 4; ++t) {
        const float* ra = rows[t];
        const float* rb = rows[t + 1];
        const float* rc = rows[t + 2];
        float m[8];
#pragma unroll
        for (int j = 0; j < 8; ++j)
            m[j] = med9(ra[j], ra[j + 1], ra[j + 2],
                        rb[j], rb[j + 1], rb[j + 2],
                        rc[j], rc[j + 1], rc[j + 2]);
        float* op = obase + ((size_t)(y0 + t) << 9) + xoff;
        *(float4*)op       = make_float4(m[0], m[1], m[2], m[3]);
        *(float4*)(op + 4) = make_float4(m[4], m[5], m[6], m[7]);
    }
}

extern "C" void kernel_launch(void* const* d_in, const int* in_sizes, int n_in,
                              void* d_out, int out_size, void* d_ws, size_t ws_size,
                              hipStream_t stream) {
    const float* x = (const float*)d_in[0];
    float* out = (float*)d_out;
    // 48 images * 128 strips/image = 6144 blocks of 1 wave.
    median3x3_kernel<<<6144, 64, 0, stream>>>(x, out);
}